// Round 7
// baseline (394.290 us; speedup 1.0000x reference)
//
#include <hip/hip_runtime.h>
#include <math.h>

#define N 8192
#define M 8192
#define C 96
#define OUT 20
#define LG 2048

#define KP 288      // packed K: [hi|hi|lo] x [hi|lo|hi], 3 sections of 96
#define NTA 64      // n-tiles in pass A (N/128)
#define NSPB 8      // m-tile stride (slices) in pass B

typedef _Float16 h8 __attribute__((ext_vector_type(8)));
typedef float    f4 __attribute__((ext_vector_type(4)));

// ---------------- workspace layout (bytes, all 256-aligned) ----------------
constexpr size_t OFF_DIFF  = 0;
constexpr size_t OFF_AL    = 256;
constexpr size_t OFF_NMF2  = OFF_AL    + (size_t)M*3*4;
constexpr size_t OFF_UPDF  = OFF_NMF2  + (size_t)N*4;
constexpr size_t OFF_GTC   = OFF_UPDF  + (size_t)M*4;
constexpr size_t OFF_SMI   = OFF_GTC   + (size_t)M*4;
constexpr size_t OFF_PERM  = OFF_SMI   + (size_t)M*4;
constexpr size_t OFF_AP    = OFF_PERM  + (size_t)M*4;            // M x 288 fp16
constexpr size_t OFF_BQ    = OFF_AP    + (size_t)M*KP*2;         // N x 288 fp16
constexpr size_t OFF_MFP   = OFF_BQ    + (size_t)N*KP*2;         // N x 288 fp16
constexpr size_t OFF_MIDQ  = OFF_MFP   + (size_t)N*KP*2;         // (M+128) x 288 fp16
constexpr size_t OFF_MIDN2 = OFF_MIDQ  + (size_t)(M+128)*KP*2;
constexpr size_t OFF_MIDC  = OFF_MIDN2 + (size_t)(M+128)*4;
constexpr size_t OFF_CLS   = OFF_MIDC  + (size_t)(M+128)*3*4;
constexpr size_t OFF_PAV   = OFF_CLS   + (size_t)(M+128)*4;      // NTA x M
constexpr size_t OFF_PAI   = OFF_PAV   + (size_t)NTA*M*4;
constexpr size_t OFF_PB    = OFF_PAI   + (size_t)NTA*M*4;        // NSPB x N x 20
constexpr size_t OFF_VALS  = OFF_PB    + (size_t)NSPB*N*OUT*4;
constexpr size_t OFF_POS   = OFF_VALS  + (size_t)LG*4;
constexpr size_t OFF_MAXV  = OFF_POS   + (size_t)N*4;
constexpr size_t OFF_AMAX  = OFF_MAXV  + (size_t)N*4;
constexpr size_t OFF_FLAGS = OFF_AMAX  + (size_t)N*4;
constexpr size_t OFF_CNT   = OFF_FLAGS + 256;
constexpr size_t OFF_META  = OFF_CNT   + 256;   // [0]=Mact [1]=ntiles [2..21]=cursor

// ---------------------------------------------------------------- 4x4 inverse
__global__ void k_diff(const float* __restrict__ posses, float* __restrict__ diff) {
    if (threadIdx.x != 0 || blockIdx.x != 0) return;
    float a[4][8];
    for (int i = 0; i < 4; i++)
        for (int j = 0; j < 4; j++) {
            a[i][j]     = posses[16 + i*4 + j];
            a[i][4 + j] = (i == j) ? 1.f : 0.f;
        }
    for (int col = 0; col < 4; col++) {
        int piv = col; float mx = fabsf(a[col][col]);
        for (int r = col + 1; r < 4; r++) {
            float v = fabsf(a[r][col]);
            if (v > mx) { mx = v; piv = r; }
        }
        if (piv != col)
            for (int j = 0; j < 8; j++) { float t = a[col][j]; a[col][j] = a[piv][j]; a[piv][j] = t; }
        float inv = 1.0f / a[col][col];
        for (int j = 0; j < 8; j++) a[col][j] *= inv;
        for (int r = 0; r < 4; r++) {
            if (r == col) continue;
            float f = a[r][col];
            for (int j = 0; j < 8; j++) a[r][j] -= f * a[col][j];
        }
    }
    for (int i = 0; i < 4; i++)
        for (int j = 0; j < 4; j++) {
            float s = 0.f;
            for (int k = 0; k < 4; k++) s += a[i][4 + k] * posses[k*4 + j];
            diff[i*4 + j] = s;
        }
}

// ---------------------------------------------------------------- per-m prep (+ class hist)
__global__ void k_prep_m(const float* __restrict__ ssf, const float* __restrict__ scoords,
                         const float* __restrict__ gt, const int* __restrict__ ran_mask,
                         const float* __restrict__ diff,
                         float* __restrict__ al, _Float16* __restrict__ aP,
                         float* __restrict__ updf, int* __restrict__ gtcls,
                         int* __restrict__ cnt) {
    __shared__ int hcnt[OUT];
    const int tt = threadIdx.x;
    if (tt < OUT) hcnt[tt] = 0;
    __syncthreads();
    int m = blockIdx.x * 256 + tt;
    {
        float x = scoords[m*3], y = scoords[m*3+1], z = scoords[m*3+2];
        #pragma unroll
        for (int j = 0; j < 3; j++)
            al[m*3 + j] = diff[j*4+0]*x + diff[j*4+1]*y + diff[j*4+2]*z + diff[j*4+3];
        const float4* r4 = (const float4*)(ssf + (size_t)m * C);
        float4 row[24]; float s = 0.f;
        #pragma unroll
        for (int c = 0; c < 24; c++) {
            float4 v = r4[c];
            row[c] = v;
            s += v.x*v.x + v.y*v.y + v.z*v.z + v.w*v.w;
        }
        float scale = 256.0f / sqrtf(s);
        h8* dst = (h8*)(aP + (size_t)m * KP);
        #pragma unroll
        for (int q = 0; q < 12; q++) {
            float4 u = row[2*q], v = row[2*q+1];
            float xs[8] = {u.x,u.y,u.z,u.w,v.x,v.y,v.z,v.w};
            h8 hi, lo;
            #pragma unroll
            for (int e = 0; e < 8; e++) {
                float xv = xs[e] * scale;
                _Float16 h = (_Float16)xv;
                hi[e] = h;
                lo[e] = (_Float16)(xv - (float)h);
            }
            dst[q] = hi; dst[12+q] = hi; dst[24+q] = lo;
        }
        int best = 0; float bv = gt[(size_t)m*OUT];
        #pragma unroll
        for (int k = 1; k < OUT; k++) {
            float v = gt[(size_t)m*OUT + k];
            if (v > bv) { bv = v; best = k; }
        }
        gtcls[m] = best;
        bool upd = (best < 9 || m < LG || ran_mask[m] == 1);
        updf[m] = upd ? 1.f : 0.f;
        if (upd) atomicAdd(&hcnt[best], 1);
    }
    __syncthreads();
    if (tt < OUT) atomicAdd(&cnt[tt], hcnt[tt]);
}

// ---------------------------------------------------------------- per-n prep
__global__ void k_prep_n(const float* __restrict__ mf, _Float16* __restrict__ bQ,
                         _Float16* __restrict__ mfP, float* __restrict__ nmf2) {
    int n = blockIdx.x * 256 + threadIdx.x;
    if (n >= N) return;
    const float4* r4 = (const float4*)(mf + (size_t)n * C);
    float4 row[24]; float s = 0.f;
    #pragma unroll
    for (int c = 0; c < 24; c++) {
        float4 v = r4[c];
        row[c] = v;
        s += v.x*v.x + v.y*v.y + v.z*v.z + v.w*v.w;
    }
    nmf2[n] = s;
    float scn = 256.0f / sqrtf(s);
    h8* dB = (h8*)(bQ  + (size_t)n * KP);
    h8* dF = (h8*)(mfP + (size_t)n * KP);
    #pragma unroll
    for (int q = 0; q < 12; q++) {
        float4 u = row[2*q], v = row[2*q+1];
        float xs[8] = {u.x,u.y,u.z,u.w,v.x,v.y,v.z,v.w};
        h8 hiN, loN, hiF, loF;
        #pragma unroll
        for (int e = 0; e < 8; e++) {
            float xn = xs[e] * scn;
            _Float16 hn = (_Float16)xn;
            hiN[e] = hn; loN[e] = (_Float16)(xn - (float)hn);
            float xf = xs[e] * 256.0f;
            _Float16 hf = (_Float16)xf;
            hiF[e] = hf; loF[e] = (_Float16)(xf - (float)hf);
        }
        dB[q] = hiN; dB[12+q] = loN; dB[24+q] = hiN;   // Q-pattern
        dF[q] = hiF; dF[12+q] = hiF; dF[24+q] = loF;   // P-pattern
    }
}

// ---------------------------------------------------------------- pass A: MFMA argmin
// 128m x 128n tile, 8 waves in 2x4 (wm: 64 m-rows, wn: 32 n-cols), fragment-major LDS
// (slot-major h8[12][128]: lane reads are 8-lane-contiguous -> conflict-free).
__global__ __launch_bounds__(512, 4) void k_argmin(
        const _Float16* __restrict__ aP, const _Float16* __restrict__ bQ,
        const float* __restrict__ al, const float* __restrict__ ori,
        float* __restrict__ pav, int* __restrict__ pai) {
    __shared__ h8 sA[12*128];
    __shared__ h8 sB[12*128];
    __shared__ float s_mc[128*3], s_nc[128*3];
    __shared__ float xv[4*128];
    __shared__ int   xi[4*128];
    const int t = threadIdx.x;
    const int wave = t >> 6, lane = t & 63;
    const int col = lane & 15, quad = lane >> 4;
    const int wm = wave >> 2, wn = wave & 3;
    const int m0 = blockIdx.x * 128, n0 = blockIdx.y * 128;
    const int quarter = t >> 7, rr = t & 127;   // staging: 4 quarters x 128 rows

    for (int i = t; i < 384; i += 512) {
        s_mc[i] = al[(size_t)m0*3 + i];
        s_nc[i] = ori[(size_t)n0*3 + i];
    }

    f4 acc[4][2];
    #pragma unroll
    for (int i = 0; i < 4; i++)
        #pragma unroll
        for (int j = 0; j < 2; j++) acc[i][j] = (f4){0.f,0.f,0.f,0.f};

    for (int kc = 0; kc < 3; kc++) {
        __syncthreads();
        {
            const h8* gA = (const h8*)(aP + (size_t)(m0+rr)*KP + kc*96) + quarter*3;
            const h8* gB = (const h8*)(bQ + (size_t)(n0+rr)*KP + kc*96) + quarter*3;
            #pragma unroll
            for (int q = 0; q < 3; q++) {
                sA[(quarter*3+q)*128 + rr] = gA[q];
                sB[(quarter*3+q)*128 + rr] = gB[q];
            }
        }
        __syncthreads();
        #pragma unroll
        for (int ks = 0; ks < 3; ks++) {
            h8 af[4], bf[2];
            #pragma unroll
            for (int i = 0; i < 4; i++)
                af[i] = sA[(ks*4+quad)*128 + wm*64 + i*16 + col];
            #pragma unroll
            for (int j = 0; j < 2; j++)
                bf[j] = sB[(ks*4+quad)*128 + wn*32 + j*16 + col];
            #pragma unroll
            for (int i = 0; i < 4; i++)
                #pragma unroll
                for (int j = 0; j < 2; j++)
                    acc[i][j] = __builtin_amdgcn_mfma_f32_16x16x32_f16(af[i], bf[j], acc[i][j], 0, 0, 0);
        }
    }

    // epilogue: sim + per-row argmin (rows m: ti,quad,g; cols n: tj,col)
    float best[4][4]; int bidx[4][4];
    #pragma unroll
    for (int i = 0; i < 4; i++)
        #pragma unroll
        for (int g = 0; g < 4; g++) { best[i][g] = 3.4e38f; bidx[i][g] = 0; }

    #pragma unroll
    for (int tj = 0; tj < 2; tj++) {
        int nl = wn*32 + tj*16 + col;
        int n  = n0 + nl;
        float ncx = s_nc[nl*3+0], ncy = s_nc[nl*3+1], ncz = s_nc[nl*3+2];
        #pragma unroll
        for (int ti = 0; ti < 4; ti++) {
            #pragma unroll
            for (int g = 0; g < 4; g++) {
                int ml = wm*64 + ti*16 + quad*4 + g;
                float dot = acc[ti][tj][g] * (1.0f/65536.0f);
                float dx = s_mc[ml*3+0]-ncx, dy = s_mc[ml*3+1]-ncy, dz = s_mc[ml*3+2]-ncz;
                float d2 = dx*dx + dy*dy + dz*dz;
                float sim = 2.0f - dot - __expf(-2.0f*d2);
                if (sim < best[ti][g]) { best[ti][g] = sim; bidx[ti][g] = n; }
            }
        }
    }
    // butterfly over the 16 col-lanes
    #pragma unroll
    for (int ti = 0; ti < 4; ti++) {
        #pragma unroll
        for (int g = 0; g < 4; g++) {
            float bv = best[ti][g]; int bi = bidx[ti][g];
            #pragma unroll
            for (int d = 1; d < 16; d <<= 1) {
                float ov = __shfl_xor(bv, d, 64);
                int   oi = __shfl_xor(bi, d, 64);
                if (ov < bv || (ov == bv && oi < bi)) { bv = ov; bi = oi; }
            }
            best[ti][g] = bv; bidx[ti][g] = bi;
        }
    }
    if (col == 0) {
        #pragma unroll
        for (int ti = 0; ti < 4; ti++)
            #pragma unroll
            for (int g = 0; g < 4; g++) {
                int ml = wm*64 + ti*16 + quad*4 + g;
                xv[wn*128 + ml] = best[ti][g];
                xi[wn*128 + ml] = bidx[ti][g];
            }
    }
    __syncthreads();
    if (t < 128) {   // single writer per (tile, m)
        float bv = xv[t]; int bi = xi[t];
        #pragma unroll
        for (int w = 1; w < 4; w++) {
            float v = xv[w*128 + t]; int i2 = xi[w*128 + t];
            if (v < bv || (v == bv && i2 < bi)) { bv = v; bi = i2; }
        }
        pav[(size_t)blockIdx.y * M + m0 + t] = bv;
        pai[(size_t)blockIdx.y * M + m0 + t] = bi;
    }
}

__global__ void k_argmin_reduce(const float* __restrict__ pav, const int* __restrict__ pai,
                                int* __restrict__ smi, float* __restrict__ out_smi) {
    int m = blockIdx.x * 256 + threadIdx.x;
    if (m >= M) return;
    float best = 3.4e38f; int bidx = 0;
    for (int sp = 0; sp < NTA; sp++) {
        float v = pav[(size_t)sp * M + m];
        int   i = pai[(size_t)sp * M + m];
        if (v < best || (v == best && i < bidx)) { best = v; bidx = i; }
    }
    smi[m] = bidx;
    out_smi[m] = (float)bidx;
}

// ---------------------------------------------------------------- scan + permute (counting sort)
__global__ void k_scan(const int* __restrict__ cnt, int* __restrict__ meta) {
    if (threadIdx.x != 0 || blockIdx.x != 0) return;
    int run = 0;
    for (int k = 0; k < OUT; k++) { meta[2 + k] = run; run += cnt[k]; }
    meta[0] = run;
    meta[1] = (run + 127) / 128;
}

__global__ void k_permute(const int* __restrict__ gtcls, const float* __restrict__ updf,
                          int* __restrict__ meta, int* __restrict__ perm) {
    int m = blockIdx.x * 256 + threadIdx.x;
    if (m >= M) return;
    if (updf[m] == 0.f) return;
    int pos = atomicAdd(&meta[2 + gtcls[m]], 1);
    perm[pos] = m;
}

// gather sorted+compacted mid rows, Q-pattern reorder from mfP ([hi|hi|lo] -> [hi|lo|hi])
__global__ void k_gather_sorted(const int* __restrict__ meta, const int* __restrict__ perm,
                                const int* __restrict__ smi, const int* __restrict__ gtcls,
                                const _Float16* __restrict__ mfP, const float* __restrict__ nmf2,
                                const float* __restrict__ ori,
                                _Float16* __restrict__ midQ, float* __restrict__ midn2,
                                float* __restrict__ midc, int* __restrict__ cls_s) {
    int rr = blockIdx.x * 256 + threadIdx.x;
    int mact = meta[0];
    int mpad = meta[1] * 128;
    if (rr < mact) {
        int m = perm[rr];
        int s = smi[m];
        const h8* src = (const h8*)(mfP + (size_t)s * KP);
        h8* dst = (h8*)(midQ + (size_t)rr * KP);
        #pragma unroll
        for (int q = 0; q < 12; q++) {
            h8 hi = src[q], lo = src[24+q];
            dst[q] = hi; dst[12+q] = lo; dst[24+q] = hi;
        }
        midn2[rr] = nmf2[s];
        midc[rr*3+0] = ori[s*3+0];
        midc[rr*3+1] = ori[s*3+1];
        midc[rr*3+2] = ori[s*3+2];
        cls_s[rr] = gtcls[m];
    } else if (rr < mpad) {
        h8 z = (h8)(_Float16)0.f;
        h8* dst = (h8*)(midQ + (size_t)rr * KP);
        #pragma unroll
        for (int q = 0; q < 36; q++) dst[q] = z;
        midn2[rr] = 1e9f;     // w = exp(-5.55e9) == 0 exactly
        midc[rr*3+0] = 0.f; midc[rr*3+1] = 0.f; midc[rr*3+2] = 0.f;
        cls_s[rr] = 0;
    }
}

// ---------------------------------------------------------------- pass B: MFMA class-binned sums
__global__ __launch_bounds__(512, 4) void k_uw(
        const _Float16* __restrict__ mfP, const _Float16* __restrict__ midQ,
        const float* __restrict__ nmf2, const float* __restrict__ ori,
        const float* __restrict__ midn2, const float* __restrict__ midc,
        const int* __restrict__ cls_s, const int* __restrict__ meta,
        float* __restrict__ pb) {
    __shared__ h8 sM[12*128];   // mid rows  (MFMA A: rows m')
    __shared__ h8 sN[12*128];   // mf n-rows (MFMA B: rows n)
    __shared__ float bins[128*21];
    __shared__ float s_nc[128*3], s_mc[128*3];
    __shared__ float s_n2[128], s_m2[128];
    __shared__ int   s_cl[128];
    const int t = threadIdx.x;
    const int wave = t >> 6, lane = t & 63;
    const int col = lane & 15, quad = lane >> 4;
    const int wm = wave >> 2, wn = wave & 3;
    const int n0 = blockIdx.x * 128;
    const int sp = blockIdx.y;
    const int ntiles = meta[1];
    const int quarter = t >> 7, rr = t & 127;

    for (int i = t; i < 128*21; i += 512) bins[i] = 0.f;
    for (int i = t; i < 384; i += 512) s_nc[i] = ori[(size_t)n0*3 + i];
    if (t < 128) s_n2[t] = nmf2[n0 + t];

    for (int mt = sp; mt < ntiles; mt += NSPB) {
        const int mb = mt * 128;
        __syncthreads();   // prev epilogue reads of aux done before overwrite
        if (t < 128) { s_m2[t] = midn2[mb + t]; s_cl[t] = cls_s[mb + t]; }
        for (int i = t; i < 384; i += 512) s_mc[i] = midc[(size_t)mb*3 + i];

        f4 acc[4][2];
        #pragma unroll
        for (int i = 0; i < 4; i++)
            #pragma unroll
            for (int j = 0; j < 2; j++) acc[i][j] = (f4){0.f,0.f,0.f,0.f};

        for (int kc = 0; kc < 3; kc++) {
            __syncthreads();
            {
                const h8* gM = (const h8*)(midQ + (size_t)(mb+rr)*KP + kc*96) + quarter*3;
                const h8* gN = (const h8*)(mfP  + (size_t)(n0+rr)*KP + kc*96) + quarter*3;
                #pragma unroll
                for (int q = 0; q < 3; q++) {
                    sM[(quarter*3+q)*128 + rr] = gM[q];
                    sN[(quarter*3+q)*128 + rr] = gN[q];
                }
            }
            __syncthreads();
            #pragma unroll
            for (int ks = 0; ks < 3; ks++) {
                h8 af[4], bf[2];
                #pragma unroll
                for (int i = 0; i < 4; i++)
                    af[i] = sM[(ks*4+quad)*128 + wm*64 + i*16 + col];
                #pragma unroll
                for (int j = 0; j < 2; j++)
                    bf[j] = sN[(ks*4+quad)*128 + wn*32 + j*16 + col];
                #pragma unroll
                for (int i = 0; i < 4; i++)
                    #pragma unroll
                    for (int j = 0; j < 2; j++)
                        acc[i][j] = __builtin_amdgcn_mfma_f32_16x16x32_f16(af[i], bf[j], acc[i][j], 0, 0, 0);
            }
        }
        // epilogue: rows m' ascending per lane -> run-length flush by class
        #pragma unroll
        for (int tj = 0; tj < 2; tj++) {
            int nl = wn*32 + tj*16 + col;
            float n2 = s_n2[nl];
            float ncx = s_nc[nl*3+0], ncy = s_nc[nl*3+1], ncz = s_nc[nl*3+2];
            float cur = 0.f; int curc = -1;
            #pragma unroll
            for (int ti = 0; ti < 4; ti++) {
                #pragma unroll
                for (int g = 0; g < 4; g++) {
                    int ml = wm*64 + ti*16 + quad*4 + g;
                    float dot = acc[ti][tj][g] * (1.0f/65536.0f);
                    float fd = fmaxf(n2 + s_m2[ml] - 2.0f*dot, 0.0f);
                    float dx = ncx - s_mc[ml*3+0], dy = ncy - s_mc[ml*3+1], dz = ncz - s_mc[ml*3+2];
                    float dc = dx*dx + dy*dy + dz*dz;
                    float w = __expf(-8.0f*dc - (0.5f/0.09f)*fd);
                    int c = s_cl[ml];
                    if (c != curc) {
                        if (curc >= 0) atomicAdd(&bins[nl*21 + curc], cur);
                        curc = c; cur = 0.f;
                    }
                    cur += w;
                }
            }
            if (curc >= 0) atomicAdd(&bins[nl*21 + curc], cur);
        }
    }
    __syncthreads();
    for (int i = t; i < 128*OUT; i += 512) {
        int loc = i / OUT, k = i - loc*OUT;
        pb[((size_t)sp*N + n0 + loc)*OUT + k] = bins[loc*21 + k];
    }
}

__global__ void k_uw_final(const float* __restrict__ pb, const float* __restrict__ svp,
                           float* __restrict__ out_uw, float* __restrict__ out_spu) {
    int n = blockIdx.x * 256 + threadIdx.x;
    if (n >= N) return;
    float s[OUT];
    #pragma unroll
    for (int k = 0; k < OUT; k++) s[k] = 0.f;
    for (int sp = 0; sp < NSPB; sp++) {
        size_t base = ((size_t)sp * N + n) * OUT;
        #pragma unroll
        for (int k = 0; k < OUT; k++) s[k] += pb[base + k];
    }
    float tot = 0.f;
    #pragma unroll
    for (int k = 0; k < OUT; k++) tot += s[k];
    float rden = 1.0f / (tot + 1e-16f);
    float p[OUT]; float mx = -3.4e38f;
    #pragma unroll
    for (int k = 0; k < OUT; k++) { p[k] = svp[(size_t)n*OUT + k]; mx = fmaxf(mx, p[k]); }
    float es = 0.f;
    #pragma unroll
    for (int k = 0; k < OUT; k++) { p[k] = __expf(p[k] - mx); es += p[k]; }
    float res = 1.0f / es;
    #pragma unroll
    for (int k = 0; k < OUT; k++) {
        float uw = s[k] * rden;
        out_uw[(size_t)n*OUT + k] = uw;
        out_spu[(size_t)n*OUT + k] = 0.5f * (p[k] * res) + 0.5f * uw;
    }
}

// ---------------------------------------------------------------- scatter (lg rows, last-wins)
__global__ void k_scatter_pre(const int* __restrict__ smi, const int* __restrict__ gtcls,
                              const float* __restrict__ spu, float* __restrict__ vals,
                              int* __restrict__ pos, int* __restrict__ flags) {
    int i = blockIdx.x * 256 + threadIdx.x;
    if (i >= LG) return;
    int idx = smi[i];
    float v = spu[(size_t)idx*OUT + gtcls[i]];
    vals[i] = v;
    if (v > 0.1f) atomicOr(&flags[0], 1);
    atomicMax(&pos[idx], i);
}

__global__ void k_scatter_apply(const int* __restrict__ smi, const int* __restrict__ gtcls,
                                const float* __restrict__ vals, const int* __restrict__ pos,
                                const int* __restrict__ flags, float* __restrict__ spu) {
    int i = blockIdx.x * 256 + threadIdx.x;
    if (i >= LG) return;
    int idx = smi[i];
    if (pos[idx] != i) return;
    float v = vals[i];
    bool tmp = flags[0] ? (v > 0.1f) : (v > 0.0f);
    if (!tmp) return;
    int cls = gtcls[i];
    #pragma unroll
    for (int k = 0; k < OUT; k++) spu[(size_t)idx*OUT + k] = (k == cls) ? 1.0f : 0.0f;
}

// ---------------------------------------------------------------- trust / finalize
__global__ void k_trust_pre(const float* __restrict__ spu, float* __restrict__ maxv,
                            int* __restrict__ amax, int* __restrict__ flags) {
    int n = blockIdx.x * 256 + threadIdx.x;
    if (n >= N) return;
    float best = spu[(size_t)n*OUT]; int bi = 0;
    #pragma unroll
    for (int k = 1; k < OUT; k++) {
        float v = spu[(size_t)n*OUT + k];
        if (v > best) { best = v; bi = k; }
    }
    maxv[n] = best; amax[n] = bi;
    if (best >= 0.9f) atomicOr(&flags[1], 1);
}

__global__ void k_finalize(const float* __restrict__ mf, const float* __restrict__ ori,
                           const float* __restrict__ maxv, const int* __restrict__ amax,
                           const int* __restrict__ flags,
                           float* __restrict__ out_trust, float* __restrict__ out_mf,
                           float* __restrict__ out_ori, float* __restrict__ out_pre) {
    int n = blockIdx.x * 256 + threadIdx.x;
    if (n >= N) return;
    float mv = maxv[n];
    bool tr = flags[1] ? (mv >= 0.9f) : (mv >= 0.85f);
    float m = tr ? 1.f : 0.f;
    out_trust[n] = m;
    const float4* src = (const float4*)(mf + (size_t)n * C);
    float4* dst = (float4*)(out_mf + (size_t)n * C);
    #pragma unroll
    for (int c = 0; c < 24; c++) {
        float4 v = src[c];
        v.x *= m; v.y *= m; v.z *= m; v.w *= m;
        dst[c] = v;
    }
    out_ori[n*3]   = ori[n*3]   * m;
    out_ori[n*3+1] = ori[n*3+1] * m;
    out_ori[n*3+2] = ori[n*3+2] * m;
    int bi = amax[n];
    #pragma unroll
    for (int k = 0; k < OUT; k++) out_pre[(size_t)n*OUT + k] = (k == bi) ? m : 0.f;
}

// ---------------------------------------------------------------- launch
extern "C" void kernel_launch(void* const* d_in, const int* in_sizes, int n_in,
                              void* d_out, int out_size, void* d_ws, size_t ws_size,
                              hipStream_t stream) {
    (void)in_sizes; (void)n_in; (void)out_size; (void)ws_size;
    const float* ssf     = (const float*)d_in[0];
    const float* scoords = (const float*)d_in[1];
    const float* gt      = (const float*)d_in[2];
    const float* svp     = (const float*)d_in[3];
    const float* mf      = (const float*)d_in[4];
    const float* ori     = (const float*)d_in[5];
    const float* posses  = (const float*)d_in[6];
    const int*   ran     = (const int*)d_in[7];

    float* out = (float*)d_out;
    float* out_trust = out;
    float* out_mf    = out_trust + N;
    float* out_ori   = out_mf + (size_t)N*C;
    float* out_pre   = out_ori + (size_t)N*3;
    float* out_uw    = out_pre + (size_t)N*OUT;
    float* out_spu   = out_uw  + (size_t)N*OUT;
    float* out_smi   = out_spu + (size_t)N*OUT;

    char* ws = (char*)d_ws;
    float*     w_diff  = (float*)(ws + OFF_DIFF);
    float*     w_al    = (float*)(ws + OFF_AL);
    float*     w_nmf2  = (float*)(ws + OFF_NMF2);
    float*     w_updf  = (float*)(ws + OFF_UPDF);
    int*       w_gtc   = (int*)(ws + OFF_GTC);
    int*       w_smi   = (int*)(ws + OFF_SMI);
    int*       w_perm  = (int*)(ws + OFF_PERM);
    _Float16*  w_aP    = (_Float16*)(ws + OFF_AP);
    _Float16*  w_bQ    = (_Float16*)(ws + OFF_BQ);
    _Float16*  w_mfP   = (_Float16*)(ws + OFF_MFP);
    _Float16*  w_midQ  = (_Float16*)(ws + OFF_MIDQ);
    float*     w_midn2 = (float*)(ws + OFF_MIDN2);
    float*     w_midc  = (float*)(ws + OFF_MIDC);
    int*       w_cls   = (int*)(ws + OFF_CLS);
    float*     w_pav   = (float*)(ws + OFF_PAV);
    int*       w_pai   = (int*)(ws + OFF_PAI);
    float*     w_pb    = (float*)(ws + OFF_PB);
    float*     w_vals  = (float*)(ws + OFF_VALS);
    int*       w_pos   = (int*)(ws + OFF_POS);
    float*     w_maxv  = (float*)(ws + OFF_MAXV);
    int*       w_amax  = (int*)(ws + OFF_AMAX);
    int*       w_flags = (int*)(ws + OFF_FLAGS);
    int*       w_cnt   = (int*)(ws + OFF_CNT);
    int*       w_meta  = (int*)(ws + OFF_META);

    hipMemsetAsync(w_pos, 0xFF, (size_t)N*4, stream);   // -1
    hipMemsetAsync(w_flags, 0, 8, stream);
    hipMemsetAsync(w_cnt, 0, OUT*4, stream);

    k_diff<<<1, 64, 0, stream>>>(posses, w_diff);
    k_prep_m<<<M/256, 256, 0, stream>>>(ssf, scoords, gt, ran, w_diff,
                                        w_al, w_aP, w_updf, w_gtc, w_cnt);
    k_prep_n<<<N/256, 256, 0, stream>>>(mf, w_bQ, w_mfP, w_nmf2);
    k_argmin<<<dim3(M/128, NTA), 512, 0, stream>>>(w_aP, w_bQ, w_al, ori, w_pav, w_pai);
    k_argmin_reduce<<<M/256, 256, 0, stream>>>(w_pav, w_pai, w_smi, out_smi);
    k_scan<<<1, 64, 0, stream>>>(w_cnt, w_meta);
    k_permute<<<M/256, 256, 0, stream>>>(w_gtc, w_updf, w_meta, w_perm);
    k_gather_sorted<<<(M+128)/256, 256, 0, stream>>>(w_meta, w_perm, w_smi, w_gtc,
                                                     w_mfP, w_nmf2, ori,
                                                     w_midQ, w_midn2, w_midc, w_cls);
    k_uw<<<dim3(N/128, NSPB), 512, 0, stream>>>(w_mfP, w_midQ, w_nmf2, ori,
                                                w_midn2, w_midc, w_cls, w_meta, w_pb);
    k_uw_final<<<N/256, 256, 0, stream>>>(w_pb, svp, out_uw, out_spu);
    k_scatter_pre<<<LG/256, 256, 0, stream>>>(w_smi, w_gtc, out_spu, w_vals, w_pos, w_flags);
    k_scatter_apply<<<LG/256, 256, 0, stream>>>(w_smi, w_gtc, w_vals, w_pos, w_flags, out_spu);
    k_trust_pre<<<N/256, 256, 0, stream>>>(out_spu, w_maxv, w_amax, w_flags);
    k_finalize<<<N/256, 256, 0, stream>>>(mf, ori, w_maxv, w_amax, w_flags,
                                          out_trust, out_mf, out_ori, out_pre);
}

// Round 8
// 374.425 us; speedup vs baseline: 1.0531x; 1.0531x over previous
//
#include <hip/hip_runtime.h>
#include <math.h>

#define N 8192
#define M 8192
#define C 96
#define OUT 20
#define LG 2048

#define KP 288      // packed K: [hi|hi|lo] x [hi|lo|hi], 3 sections of 96 (36 h8 slots)
#define NTA 64      // n-tiles in pass A (N/128)
#define NSPB 8      // m-tile stride (slices) in pass B

typedef _Float16 h8 __attribute__((ext_vector_type(8)));
typedef float    f4 __attribute__((ext_vector_type(4)));

// tile-slot-major h8 index: rows grouped in 128-row tiles, slot-major inside
__device__ __forceinline__ size_t tsm(int row, int slot) {
    return ((size_t)(row >> 7) * 36 + slot) * 128 + (row & 127);
}

// ---------------- workspace layout (bytes, all 256-aligned) ----------------
constexpr size_t OFF_DIFF  = 0;
constexpr size_t OFF_AL    = 256;
constexpr size_t OFF_NMF2  = OFF_AL    + (size_t)M*3*4;
constexpr size_t OFF_UPDF  = OFF_NMF2  + (size_t)N*4;
constexpr size_t OFF_GTC   = OFF_UPDF  + (size_t)M*4;
constexpr size_t OFF_SMI   = OFF_GTC   + (size_t)M*4;
constexpr size_t OFF_PERM  = OFF_SMI   + (size_t)M*4;
constexpr size_t OFF_AP    = OFF_PERM  + (size_t)M*4;            // M x 288 fp16 (tsm)
constexpr size_t OFF_BQ    = OFF_AP    + (size_t)M*KP*2;         // N x 288 fp16 (tsm)
constexpr size_t OFF_MFP   = OFF_BQ    + (size_t)N*KP*2;         // N x 288 fp16 (tsm)
constexpr size_t OFF_MIDQ  = OFF_MFP   + (size_t)N*KP*2;         // (M+128) x 288 fp16 (tsm)
constexpr size_t OFF_MIDN2 = OFF_MIDQ  + (size_t)(M+128)*KP*2;
constexpr size_t OFF_MIDC  = OFF_MIDN2 + (size_t)(M+128)*4;
constexpr size_t OFF_CLS   = OFF_MIDC  + (size_t)(M+128)*3*4;
constexpr size_t OFF_PAV   = OFF_CLS   + (size_t)(M+128)*4;      // NTA x M
constexpr size_t OFF_PAI   = OFF_PAV   + (size_t)NTA*M*4;
constexpr size_t OFF_PB    = OFF_PAI   + (size_t)NTA*M*4;        // NSPB x N x 20
constexpr size_t OFF_VALS  = OFF_PB    + (size_t)NSPB*N*OUT*4;
constexpr size_t OFF_POS   = OFF_VALS  + (size_t)LG*4;
constexpr size_t OFF_MAXV  = OFF_POS   + (size_t)N*4;
constexpr size_t OFF_AMAX  = OFF_MAXV  + (size_t)N*4;
constexpr size_t OFF_FLAGS = OFF_AMAX  + (size_t)N*4;
constexpr size_t OFF_CNT   = OFF_FLAGS + 256;
constexpr size_t OFF_META  = OFF_CNT   + 256;   // [0]=Mact [1]=ntiles [2..21]=cursor

// ---------------------------------------------------------------- 4x4 inverse
__global__ void k_diff(const float* __restrict__ posses, float* __restrict__ diff) {
    if (threadIdx.x != 0 || blockIdx.x != 0) return;
    float a[4][8];
    for (int i = 0; i < 4; i++)
        for (int j = 0; j < 4; j++) {
            a[i][j]     = posses[16 + i*4 + j];
            a[i][4 + j] = (i == j) ? 1.f : 0.f;
        }
    for (int col = 0; col < 4; col++) {
        int piv = col; float mx = fabsf(a[col][col]);
        for (int r = col + 1; r < 4; r++) {
            float v = fabsf(a[r][col]);
            if (v > mx) { mx = v; piv = r; }
        }
        if (piv != col)
            for (int j = 0; j < 8; j++) { float t = a[col][j]; a[col][j] = a[piv][j]; a[piv][j] = t; }
        float inv = 1.0f / a[col][col];
        for (int j = 0; j < 8; j++) a[col][j] *= inv;
        for (int r = 0; r < 4; r++) {
            if (r == col) continue;
            float f = a[r][col];
            for (int j = 0; j < 8; j++) a[r][j] -= f * a[col][j];
        }
    }
    for (int i = 0; i < 4; i++)
        for (int j = 0; j < 4; j++) {
            float s = 0.f;
            for (int k = 0; k < 4; k++) s += a[i][4 + k] * posses[k*4 + j];
            diff[i*4 + j] = s;
        }
}

// ---------------------------------------------------------------- per-m prep (+ class hist)
__global__ void k_prep_m(const float* __restrict__ ssf, const float* __restrict__ scoords,
                         const float* __restrict__ gt, const int* __restrict__ ran_mask,
                         const float* __restrict__ diff,
                         float* __restrict__ al, _Float16* __restrict__ aP,
                         float* __restrict__ updf, int* __restrict__ gtcls,
                         int* __restrict__ cnt) {
    __shared__ int hcnt[OUT];
    const int tt = threadIdx.x;
    if (tt < OUT) hcnt[tt] = 0;
    __syncthreads();
    int m = blockIdx.x * 256 + tt;
    {
        float x = scoords[m*3], y = scoords[m*3+1], z = scoords[m*3+2];
        #pragma unroll
        for (int j = 0; j < 3; j++)
            al[m*3 + j] = diff[j*4+0]*x + diff[j*4+1]*y + diff[j*4+2]*z + diff[j*4+3];
        const float4* r4 = (const float4*)(ssf + (size_t)m * C);
        float4 row[24]; float s = 0.f;
        #pragma unroll
        for (int c = 0; c < 24; c++) {
            float4 v = r4[c];
            row[c] = v;
            s += v.x*v.x + v.y*v.y + v.z*v.z + v.w*v.w;
        }
        float scale = 256.0f / sqrtf(s);
        h8* dst = (h8*)aP;
        #pragma unroll
        for (int q = 0; q < 12; q++) {
            float4 u = row[2*q], v = row[2*q+1];
            float xs[8] = {u.x,u.y,u.z,u.w,v.x,v.y,v.z,v.w};
            h8 hi, lo;
            #pragma unroll
            for (int e = 0; e < 8; e++) {
                float xv = xs[e] * scale;
                _Float16 h = (_Float16)xv;
                hi[e] = h;
                lo[e] = (_Float16)(xv - (float)h);
            }
            dst[tsm(m, q)]      = hi;
            dst[tsm(m, 12 + q)] = hi;
            dst[tsm(m, 24 + q)] = lo;
        }
        int best = 0; float bv = gt[(size_t)m*OUT];
        #pragma unroll
        for (int k = 1; k < OUT; k++) {
            float v = gt[(size_t)m*OUT + k];
            if (v > bv) { bv = v; best = k; }
        }
        gtcls[m] = best;
        bool upd = (best < 9 || m < LG || ran_mask[m] == 1);
        updf[m] = upd ? 1.f : 0.f;
        if (upd) atomicAdd(&hcnt[best], 1);
    }
    __syncthreads();
    if (tt < OUT) atomicAdd(&cnt[tt], hcnt[tt]);
}

// ---------------------------------------------------------------- per-n prep
__global__ void k_prep_n(const float* __restrict__ mf, _Float16* __restrict__ bQ,
                         _Float16* __restrict__ mfP, float* __restrict__ nmf2) {
    int n = blockIdx.x * 256 + threadIdx.x;
    if (n >= N) return;
    const float4* r4 = (const float4*)(mf + (size_t)n * C);
    float4 row[24]; float s = 0.f;
    #pragma unroll
    for (int c = 0; c < 24; c++) {
        float4 v = r4[c];
        row[c] = v;
        s += v.x*v.x + v.y*v.y + v.z*v.z + v.w*v.w;
    }
    nmf2[n] = s;
    float scn = 256.0f / sqrtf(s);
    h8* dB = (h8*)bQ;
    h8* dF = (h8*)mfP;
    #pragma unroll
    for (int q = 0; q < 12; q++) {
        float4 u = row[2*q], v = row[2*q+1];
        float xs[8] = {u.x,u.y,u.z,u.w,v.x,v.y,v.z,v.w};
        h8 hiN, loN, hiF, loF;
        #pragma unroll
        for (int e = 0; e < 8; e++) {
            float xn = xs[e] * scn;
            _Float16 hn = (_Float16)xn;
            hiN[e] = hn; loN[e] = (_Float16)(xn - (float)hn);
            float xf = xs[e] * 256.0f;
            _Float16 hf = (_Float16)xf;
            hiF[e] = hf; loF[e] = (_Float16)(xf - (float)hf);
        }
        dB[tsm(n, q)]      = hiN;   // Q-pattern: [hi|lo|hi]
        dB[tsm(n, 12+q)]   = loN;
        dB[tsm(n, 24+q)]   = hiN;
        dF[tsm(n, q)]      = hiF;   // P-pattern: [hi|hi|lo]
        dF[tsm(n, 12+q)]   = hiF;
        dF[tsm(n, 24+q)]   = loF;
    }
}

// ---------------------------------------------------------------- pass A: MFMA argmin
// 128m x 128n tile, 8 waves in 2x4; tile-slot-major global -> coalesced staging;
// fragment-major LDS -> conflict-free reads.
__global__ __launch_bounds__(512, 4) void k_argmin(
        const _Float16* __restrict__ aP, const _Float16* __restrict__ bQ,
        const float* __restrict__ al, const float* __restrict__ ori,
        float* __restrict__ pav, int* __restrict__ pai) {
    __shared__ h8 sA[12*128];
    __shared__ h8 sB[12*128];
    __shared__ float s_mc[128*3], s_nc[128*3];
    __shared__ float xv[4*128];
    __shared__ int   xi[4*128];
    const int t = threadIdx.x;
    const int wave = t >> 6, lane = t & 63;
    const int col = lane & 15, quad = lane >> 4;
    const int wm = wave >> 2, wn = wave & 3;
    const int m0 = blockIdx.x * 128, n0 = blockIdx.y * 128;
    const int quarter = t >> 7, rr = t & 127;   // staging: 4 quarters x 128 rows

    const h8* gA = (const h8*)aP + (size_t)blockIdx.x * 36 * 128;
    const h8* gB = (const h8*)bQ + (size_t)blockIdx.y * 36 * 128;

    for (int i = t; i < 384; i += 512) {
        s_mc[i] = al[(size_t)m0*3 + i];
        s_nc[i] = ori[(size_t)n0*3 + i];
    }

    f4 acc[4][2];
    #pragma unroll
    for (int i = 0; i < 4; i++)
        #pragma unroll
        for (int j = 0; j < 2; j++) acc[i][j] = (f4){0.f,0.f,0.f,0.f};

    for (int kc = 0; kc < 3; kc++) {
        __syncthreads();
        {
            #pragma unroll
            for (int q = 0; q < 3; q++) {
                int ls = quarter*3 + q;             // local slot 0..11
                int gs = kc*12 + ls;                // global slot 0..35
                sA[ls*128 + rr] = gA[(size_t)gs*128 + rr];   // 64-lane contiguous
                sB[ls*128 + rr] = gB[(size_t)gs*128 + rr];
            }
        }
        __syncthreads();
        #pragma unroll
        for (int ks = 0; ks < 3; ks++) {
            h8 af[4], bf[2];
            #pragma unroll
            for (int i = 0; i < 4; i++)
                af[i] = sA[(ks*4+quad)*128 + wm*64 + i*16 + col];
            #pragma unroll
            for (int j = 0; j < 2; j++)
                bf[j] = sB[(ks*4+quad)*128 + wn*32 + j*16 + col];
            #pragma unroll
            for (int i = 0; i < 4; i++)
                #pragma unroll
                for (int j = 0; j < 2; j++)
                    acc[i][j] = __builtin_amdgcn_mfma_f32_16x16x32_f16(af[i], bf[j], acc[i][j], 0, 0, 0);
        }
    }

    // epilogue: sim + per-row argmin (rows m: ti,quad,g; cols n: tj,col)
    float best[4][4]; int bidx[4][4];
    #pragma unroll
    for (int i = 0; i < 4; i++)
        #pragma unroll
        for (int g = 0; g < 4; g++) { best[i][g] = 3.4e38f; bidx[i][g] = 0; }

    #pragma unroll
    for (int tj = 0; tj < 2; tj++) {
        int nl = wn*32 + tj*16 + col;
        int n  = n0 + nl;
        float ncx = s_nc[nl*3+0], ncy = s_nc[nl*3+1], ncz = s_nc[nl*3+2];
        #pragma unroll
        for (int ti = 0; ti < 4; ti++) {
            #pragma unroll
            for (int g = 0; g < 4; g++) {
                int ml = wm*64 + ti*16 + quad*4 + g;
                float dot = acc[ti][tj][g] * (1.0f/65536.0f);
                float dx = s_mc[ml*3+0]-ncx, dy = s_mc[ml*3+1]-ncy, dz = s_mc[ml*3+2]-ncz;
                float d2 = dx*dx + dy*dy + dz*dz;
                float sim = 2.0f - dot - __expf(-2.0f*d2);
                if (sim < best[ti][g]) { best[ti][g] = sim; bidx[ti][g] = n; }
            }
        }
    }
    // butterfly over the 16 col-lanes
    #pragma unroll
    for (int ti = 0; ti < 4; ti++) {
        #pragma unroll
        for (int g = 0; g < 4; g++) {
            float bv = best[ti][g]; int bi = bidx[ti][g];
            #pragma unroll
            for (int d = 1; d < 16; d <<= 1) {
                float ov = __shfl_xor(bv, d, 64);
                int   oi = __shfl_xor(bi, d, 64);
                if (ov < bv || (ov == bv && oi < bi)) { bv = ov; bi = oi; }
            }
            best[ti][g] = bv; bidx[ti][g] = bi;
        }
    }
    if (col == 0) {
        #pragma unroll
        for (int ti = 0; ti < 4; ti++)
            #pragma unroll
            for (int g = 0; g < 4; g++) {
                int ml = wm*64 + ti*16 + quad*4 + g;
                xv[wn*128 + ml] = best[ti][g];
                xi[wn*128 + ml] = bidx[ti][g];
            }
    }
    __syncthreads();
    if (t < 128) {   // single writer per (tile, m)
        float bv = xv[t]; int bi = xi[t];
        #pragma unroll
        for (int w = 1; w < 4; w++) {
            float v = xv[w*128 + t]; int i2 = xi[w*128 + t];
            if (v < bv || (v == bv && i2 < bi)) { bv = v; bi = i2; }
        }
        pav[(size_t)blockIdx.y * M + m0 + t] = bv;
        pai[(size_t)blockIdx.y * M + m0 + t] = bi;
    }
}

__global__ void k_argmin_reduce(const float* __restrict__ pav, const int* __restrict__ pai,
                                int* __restrict__ smi, float* __restrict__ out_smi) {
    int m = blockIdx.x * 256 + threadIdx.x;
    if (m >= M) return;
    float best = 3.4e38f; int bidx = 0;
    for (int sp = 0; sp < NTA; sp++) {
        float v = pav[(size_t)sp * M + m];
        int   i = pai[(size_t)sp * M + m];
        if (v < best || (v == best && i < bidx)) { best = v; bidx = i; }
    }
    smi[m] = bidx;
    out_smi[m] = (float)bidx;
}

// ---------------------------------------------------------------- scan + permute (counting sort)
__global__ void k_scan(const int* __restrict__ cnt, int* __restrict__ meta) {
    if (threadIdx.x != 0 || blockIdx.x != 0) return;
    int run = 0;
    for (int k = 0; k < OUT; k++) { meta[2 + k] = run; run += cnt[k]; }
    meta[0] = run;
    meta[1] = (run + 127) / 128;
}

__global__ void k_permute(const int* __restrict__ gtcls, const float* __restrict__ updf,
                          int* __restrict__ meta, int* __restrict__ perm) {
    int m = blockIdx.x * 256 + threadIdx.x;
    if (m >= M) return;
    if (updf[m] == 0.f) return;
    int pos = atomicAdd(&meta[2 + gtcls[m]], 1);
    perm[pos] = m;
}

// gather sorted+compacted mid rows (tsm layout both sides), Q-pattern reorder
__global__ void k_gather_sorted(const int* __restrict__ meta, const int* __restrict__ perm,
                                const int* __restrict__ smi, const int* __restrict__ gtcls,
                                const _Float16* __restrict__ mfP, const float* __restrict__ nmf2,
                                const float* __restrict__ ori,
                                _Float16* __restrict__ midQ, float* __restrict__ midn2,
                                float* __restrict__ midc, int* __restrict__ cls_s) {
    int rr = blockIdx.x * 256 + threadIdx.x;
    int mact = meta[0];
    int mpad = meta[1] * 128;
    const h8* src = (const h8*)mfP;
    h8* dst = (h8*)midQ;
    if (rr < mact) {
        int m = perm[rr];
        int s = smi[m];
        #pragma unroll
        for (int q = 0; q < 12; q++) {
            h8 hi = src[tsm(s, q)], lo = src[tsm(s, 24+q)];
            dst[tsm(rr, q)]    = hi;
            dst[tsm(rr, 12+q)] = lo;
            dst[tsm(rr, 24+q)] = hi;
        }
        midn2[rr] = nmf2[s];
        midc[rr*3+0] = ori[s*3+0];
        midc[rr*3+1] = ori[s*3+1];
        midc[rr*3+2] = ori[s*3+2];
        cls_s[rr] = gtcls[m];
    } else if (rr < mpad) {
        h8 z = (h8)(_Float16)0.f;
        #pragma unroll
        for (int q = 0; q < 36; q++) dst[tsm(rr, q)] = z;
        midn2[rr] = 1e9f;     // w = exp(-5.55e9) == 0 exactly
        midc[rr*3+0] = 0.f; midc[rr*3+1] = 0.f; midc[rr*3+2] = 0.f;
        cls_s[rr] = 0;
    }
}

// ---------------------------------------------------------------- pass B: MFMA class-binned sums
__global__ __launch_bounds__(512, 4) void k_uw(
        const _Float16* __restrict__ mfP, const _Float16* __restrict__ midQ,
        const float* __restrict__ nmf2, const float* __restrict__ ori,
        const float* __restrict__ midn2, const float* __restrict__ midc,
        const int* __restrict__ cls_s, const int* __restrict__ meta,
        float* __restrict__ pb) {
    __shared__ h8 sM[12*128];   // mid rows  (MFMA A: rows m')
    __shared__ h8 sN[12*128];   // mf n-rows (MFMA B: rows n)
    __shared__ float bins[128*21];
    __shared__ float s_nc[128*3], s_mc[128*3];
    __shared__ float s_n2[128], s_m2[128];
    __shared__ int   s_cl[128];
    const int t = threadIdx.x;
    const int wave = t >> 6, lane = t & 63;
    const int col = lane & 15, quad = lane >> 4;
    const int wm = wave >> 2, wn = wave & 3;
    const int n0 = blockIdx.x * 128;
    const int sp = blockIdx.y;
    const int ntiles = meta[1];
    const int quarter = t >> 7, rr = t & 127;

    const h8* gN = (const h8*)mfP + (size_t)blockIdx.x * 36 * 128;

    for (int i = t; i < 128*21; i += 512) bins[i] = 0.f;
    for (int i = t; i < 384; i += 512) s_nc[i] = ori[(size_t)n0*3 + i];
    if (t < 128) s_n2[t] = nmf2[n0 + t];

    for (int mt = sp; mt < ntiles; mt += NSPB) {
        const int mb = mt * 128;
        const h8* gM = (const h8*)midQ + (size_t)mt * 36 * 128;
        __syncthreads();   // prev epilogue reads of aux done before overwrite
        if (t < 128) { s_m2[t] = midn2[mb + t]; s_cl[t] = cls_s[mb + t]; }
        for (int i = t; i < 384; i += 512) s_mc[i] = midc[(size_t)mb*3 + i];

        f4 acc[4][2];
        #pragma unroll
        for (int i = 0; i < 4; i++)
            #pragma unroll
            for (int j = 0; j < 2; j++) acc[i][j] = (f4){0.f,0.f,0.f,0.f};

        for (int kc = 0; kc < 3; kc++) {
            __syncthreads();
            {
                #pragma unroll
                for (int q = 0; q < 3; q++) {
                    int ls = quarter*3 + q;
                    int gs = kc*12 + ls;
                    sM[ls*128 + rr] = gM[(size_t)gs*128 + rr];
                    sN[ls*128 + rr] = gN[(size_t)gs*128 + rr];
                }
            }
            __syncthreads();
            #pragma unroll
            for (int ks = 0; ks < 3; ks++) {
                h8 af[4], bf[2];
                #pragma unroll
                for (int i = 0; i < 4; i++)
                    af[i] = sM[(ks*4+quad)*128 + wm*64 + i*16 + col];
                #pragma unroll
                for (int j = 0; j < 2; j++)
                    bf[j] = sN[(ks*4+quad)*128 + wn*32 + j*16 + col];
                #pragma unroll
                for (int i = 0; i < 4; i++)
                    #pragma unroll
                    for (int j = 0; j < 2; j++)
                        acc[i][j] = __builtin_amdgcn_mfma_f32_16x16x32_f16(af[i], bf[j], acc[i][j], 0, 0, 0);
            }
        }
        // epilogue: rows m' ascending per lane -> run-length flush by class
        #pragma unroll
        for (int tj = 0; tj < 2; tj++) {
            int nl = wn*32 + tj*16 + col;
            float n2 = s_n2[nl];
            float ncx = s_nc[nl*3+0], ncy = s_nc[nl*3+1], ncz = s_nc[nl*3+2];
            float cur = 0.f; int curc = -1;
            #pragma unroll
            for (int ti = 0; ti < 4; ti++) {
                #pragma unroll
                for (int g = 0; g < 4; g++) {
                    int ml = wm*64 + ti*16 + quad*4 + g;
                    float dot = acc[ti][tj][g] * (1.0f/65536.0f);
                    float fd = fmaxf(n2 + s_m2[ml] - 2.0f*dot, 0.0f);
                    float dx = ncx - s_mc[ml*3+0], dy = ncy - s_mc[ml*3+1], dz = ncz - s_mc[ml*3+2];
                    float dc = dx*dx + dy*dy + dz*dz;
                    float w = __expf(-8.0f*dc - (0.5f/0.09f)*fd);
                    int c = s_cl[ml];
                    if (c != curc) {
                        if (curc >= 0) atomicAdd(&bins[nl*21 + curc], cur);
                        curc = c; cur = 0.f;
                    }
                    cur += w;
                }
            }
            if (curc >= 0) atomicAdd(&bins[nl*21 + curc], cur);
        }
    }
    __syncthreads();
    for (int i = t; i < 128*OUT; i += 512) {
        int loc = i / OUT, k = i - loc*OUT;
        pb[((size_t)sp*N + n0 + loc)*OUT + k] = bins[loc*21 + k];
    }
}

__global__ void k_uw_final(const float* __restrict__ pb, const float* __restrict__ svp,
                           float* __restrict__ out_uw, float* __restrict__ out_spu) {
    int n = blockIdx.x * 256 + threadIdx.x;
    if (n >= N) return;
    float s[OUT];
    #pragma unroll
    for (int k = 0; k < OUT; k++) s[k] = 0.f;
    for (int sp = 0; sp < NSPB; sp++) {
        size_t base = ((size_t)sp * N + n) * OUT;
        #pragma unroll
        for (int k = 0; k < OUT; k++) s[k] += pb[base + k];
    }
    float tot = 0.f;
    #pragma unroll
    for (int k = 0; k < OUT; k++) tot += s[k];
    float rden = 1.0f / (tot + 1e-16f);
    float p[OUT]; float mx = -3.4e38f;
    #pragma unroll
    for (int k = 0; k < OUT; k++) { p[k] = svp[(size_t)n*OUT + k]; mx = fmaxf(mx, p[k]); }
    float es = 0.f;
    #pragma unroll
    for (int k = 0; k < OUT; k++) { p[k] = __expf(p[k] - mx); es += p[k]; }
    float res = 1.0f / es;
    #pragma unroll
    for (int k = 0; k < OUT; k++) {
        float uw = s[k] * rden;
        out_uw[(size_t)n*OUT + k] = uw;
        out_spu[(size_t)n*OUT + k] = 0.5f * (p[k] * res) + 0.5f * uw;
    }
}

// ---------------------------------------------------------------- scatter (lg rows, last-wins)
__global__ void k_scatter_pre(const int* __restrict__ smi, const int* __restrict__ gtcls,
                              const float* __restrict__ spu, float* __restrict__ vals,
                              int* __restrict__ pos, int* __restrict__ flags) {
    int i = blockIdx.x * 256 + threadIdx.x;
    if (i >= LG) return;
    int idx = smi[i];
    float v = spu[(size_t)idx*OUT + gtcls[i]];
    vals[i] = v;
    if (v > 0.1f) atomicOr(&flags[0], 1);
    atomicMax(&pos[idx], i);
}

__global__ void k_scatter_apply(const int* __restrict__ smi, const int* __restrict__ gtcls,
                                const float* __restrict__ vals, const int* __restrict__ pos,
                                const int* __restrict__ flags, float* __restrict__ spu) {
    int i = blockIdx.x * 256 + threadIdx.x;
    if (i >= LG) return;
    int idx = smi[i];
    if (pos[idx] != i) return;
    float v = vals[i];
    bool tmp = flags[0] ? (v > 0.1f) : (v > 0.0f);
    if (!tmp) return;
    int cls = gtcls[i];
    #pragma unroll
    for (int k = 0; k < OUT; k++) spu[(size_t)idx*OUT + k] = (k == cls) ? 1.0f : 0.0f;
}

// ---------------------------------------------------------------- trust / finalize
__global__ void k_trust_pre(const float* __restrict__ spu, float* __restrict__ maxv,
                            int* __restrict__ amax, int* __restrict__ flags) {
    int n = blockIdx.x * 256 + threadIdx.x;
    if (n >= N) return;
    float best = spu[(size_t)n*OUT]; int bi = 0;
    #pragma unroll
    for (int k = 1; k < OUT; k++) {
        float v = spu[(size_t)n*OUT + k];
        if (v > best) { best = v; bi = k; }
    }
    maxv[n] = best; amax[n] = bi;
    if (best >= 0.9f) atomicOr(&flags[1], 1);
}

__global__ void k_finalize(const float* __restrict__ mf, const float* __restrict__ ori,
                           const float* __restrict__ maxv, const int* __restrict__ amax,
                           const int* __restrict__ flags,
                           float* __restrict__ out_trust, float* __restrict__ out_mf,
                           float* __restrict__ out_ori, float* __restrict__ out_pre) {
    int n = blockIdx.x * 256 + threadIdx.x;
    if (n >= N) return;
    float mv = maxv[n];
    bool tr = flags[1] ? (mv >= 0.9f) : (mv >= 0.85f);
    float m = tr ? 1.f : 0.f;
    out_trust[n] = m;
    const float4* src = (const float4*)(mf + (size_t)n * C);
    float4* dst = (float4*)(out_mf + (size_t)n * C);
    #pragma unroll
    for (int c = 0; c < 24; c++) {
        float4 v = src[c];
        v.x *= m; v.y *= m; v.z *= m; v.w *= m;
        dst[c] = v;
    }
    out_ori[n*3]   = ori[n*3]   * m;
    out_ori[n*3+1] = ori[n*3+1] * m;
    out_ori[n*3+2] = ori[n*3+2] * m;
    int bi = amax[n];
    #pragma unroll
    for (int k = 0; k < OUT; k++) out_pre[(size_t)n*OUT + k] = (k == bi) ? m : 0.f;
}

// ---------------------------------------------------------------- launch
extern "C" void kernel_launch(void* const* d_in, const int* in_sizes, int n_in,
                              void* d_out, int out_size, void* d_ws, size_t ws_size,
                              hipStream_t stream) {
    (void)in_sizes; (void)n_in; (void)out_size; (void)ws_size;
    const float* ssf     = (const float*)d_in[0];
    const float* scoords = (const float*)d_in[1];
    const float* gt      = (const float*)d_in[2];
    const float* svp     = (const float*)d_in[3];
    const float* mf      = (const float*)d_in[4];
    const float* ori     = (const float*)d_in[5];
    const float* posses  = (const float*)d_in[6];
    const int*   ran     = (const int*)d_in[7];

    float* out = (float*)d_out;
    float* out_trust = out;
    float* out_mf    = out_trust + N;
    float* out_ori   = out_mf + (size_t)N*C;
    float* out_pre   = out_ori + (size_t)N*3;
    float* out_uw    = out_pre + (size_t)N*OUT;
    float* out_spu   = out_uw  + (size_t)N*OUT;
    float* out_smi   = out_spu + (size_t)N*OUT;

    char* ws = (char*)d_ws;
    float*     w_diff  = (float*)(ws + OFF_DIFF);
    float*     w_al    = (float*)(ws + OFF_AL);
    float*     w_nmf2  = (float*)(ws + OFF_NMF2);
    float*     w_updf  = (float*)(ws + OFF_UPDF);
    int*       w_gtc   = (int*)(ws + OFF_GTC);
    int*       w_smi   = (int*)(ws + OFF_SMI);
    int*       w_perm  = (int*)(ws + OFF_PERM);
    _Float16*  w_aP    = (_Float16*)(ws + OFF_AP);
    _Float16*  w_bQ    = (_Float16*)(ws + OFF_BQ);
    _Float16*  w_mfP   = (_Float16*)(ws + OFF_MFP);
    _Float16*  w_midQ  = (_Float16*)(ws + OFF_MIDQ);
    float*     w_midn2 = (float*)(ws + OFF_MIDN2);
    float*     w_midc  = (float*)(ws + OFF_MIDC);
    int*       w_cls   = (int*)(ws + OFF_CLS);
    float*     w_pav   = (float*)(ws + OFF_PAV);
    int*       w_pai   = (int*)(ws + OFF_PAI);
    float*     w_pb    = (float*)(ws + OFF_PB);
    float*     w_vals  = (float*)(ws + OFF_VALS);
    int*       w_pos   = (int*)(ws + OFF_POS);
    float*     w_maxv  = (float*)(ws + OFF_MAXV);
    int*       w_amax  = (int*)(ws + OFF_AMAX);
    int*       w_flags = (int*)(ws + OFF_FLAGS);
    int*       w_cnt   = (int*)(ws + OFF_CNT);
    int*       w_meta  = (int*)(ws + OFF_META);

    hipMemsetAsync(w_pos, 0xFF, (size_t)N*4, stream);   // -1
    hipMemsetAsync(w_flags, 0, 8, stream);
    hipMemsetAsync(w_cnt, 0, OUT*4, stream);

    k_diff<<<1, 64, 0, stream>>>(posses, w_diff);
    k_prep_m<<<M/256, 256, 0, stream>>>(ssf, scoords, gt, ran, w_diff,
                                        w_al, w_aP, w_updf, w_gtc, w_cnt);
    k_prep_n<<<N/256, 256, 0, stream>>>(mf, w_bQ, w_mfP, w_nmf2);
    k_argmin<<<dim3(M/128, NTA), 512, 0, stream>>>(w_aP, w_bQ, w_al, ori, w_pav, w_pai);
    k_argmin_reduce<<<M/256, 256, 0, stream>>>(w_pav, w_pai, w_smi, out_smi);
    k_scan<<<1, 64, 0, stream>>>(w_cnt, w_meta);
    k_permute<<<M/256, 256, 0, stream>>>(w_gtc, w_updf, w_meta, w_perm);
    k_gather_sorted<<<(M+128)/256, 256, 0, stream>>>(w_meta, w_perm, w_smi, w_gtc,
                                                     w_mfP, w_nmf2, ori,
                                                     w_midQ, w_midn2, w_midc, w_cls);
    k_uw<<<dim3(N/128, NSPB), 512, 0, stream>>>(w_mfP, w_midQ, w_nmf2, ori,
                                                w_midn2, w_midc, w_cls, w_meta, w_pb);
    k_uw_final<<<N/256, 256, 0, stream>>>(w_pb, svp, out_uw, out_spu);
    k_scatter_pre<<<LG/256, 256, 0, stream>>>(w_smi, w_gtc, out_spu, w_vals, w_pos, w_flags);
    k_scatter_apply<<<LG/256, 256, 0, stream>>>(w_smi, w_gtc, w_vals, w_pos, w_flags, out_spu);
    k_trust_pre<<<N/256, 256, 0, stream>>>(out_spu, w_maxv, w_amax, w_flags);
    k_finalize<<<N/256, 256, 0, stream>>>(mf, ori, w_maxv, w_amax, w_flags,
                                          out_trust, out_mf, out_ori, out_pre);
}